// Round 10
// baseline (410.030 us; speedup 1.0000x reference)
//
#include <hip/hip_runtime.h>

#define N_NODES 20000
#define HID 64
#define NSTEPS 6
#define NSLICE 8
#define SLICE_SZ (N_NODES / NSLICE)  // 2500
#define SUBB 64                      // sub-chunks per slice (phase 2)
#define NBLK (NSLICE * SUBB)         // 512 blocks for hist/scatter
#define TBLK ((N_NODES + 63) / 64)   // 313 transpose blocks (fused into scatter)
#define NB1 512                      // blocks for count/bucket phase
#define MAGIC 13422                  // floor(d*13422 / 2^25) == d/2500 for d < 20000

typedef _Float16 h8_t __attribute__((ext_vector_type(8)));
typedef unsigned u4_t __attribute__((ext_vector_type(4)));

union U16H { unsigned short u; _Float16 h; };
union U4H8 { uint4 u; _Float16 h[8]; };

__device__ __forceinline__ _Float16 us_as_h(unsigned short s) { U16H u; u.u = s; return u.h; }
__device__ __forceinline__ unsigned short h_as_us(_Float16 h) { U16H u; u.h = h; return u.u; }

__device__ __forceinline__ int slice_of(int d) {
    return (int)(((unsigned)d * (unsigned)MAGIC) >> 25);
}
__device__ __forceinline__ float softplusf_(float x) {
    return (x > 0.f) ? (x + log1pf(expf(-x))) : log1pf(expf(x));
}
__device__ __forceinline__ float sigmoidf_(float x) {
    return 1.f / (1.f + expf(-x));
}

// ---------------- P0: per-(block,slice) edge counts + zero eg groups ----------------
__global__ __launch_bounds__(256) void count8_kernel(const int* __restrict__ edst,
                                                     int* __restrict__ gcnt, int TE,
                                                     u4_t* __restrict__ egq, long long egq_n) {
    // fused: zero the grouped-entry buffer (pad slots must read {src=0,coef=0})
    u4_t z = {0u, 0u, 0u, 0u};
    for (long long i = (long long)blockIdx.x * 256 + threadIdx.x; i < egq_n;
         i += (long long)NB1 * 256)
        __builtin_nontemporal_store(z, egq + i);

    __shared__ int lh[8];
    int bk = blockIdx.x;
    int lane = threadIdx.x & 63;
    if (threadIdx.x < 8) lh[threadIdx.x] = 0;
    __syncthreads();
    int chunk = ((TE + NB1 - 1) / NB1 + 255) & ~255;
    int lo = bk * chunk;
    int hi = min(lo + chunk, TE);
    int my = 0;
    for (int ii = 0; ii < chunk; ii += 256) {
        int i = lo + ii + (int)threadIdx.x;
        bool act = i < hi;
        int s = -1;
        if (act) s = slice_of(__builtin_nontemporal_load(edst + i));
#pragma unroll
        for (int q = 0; q < 8; ++q) {
            unsigned long long b = __ballot(s == q);
            if (lane == q) my += (int)__popcll(b);
        }
    }
    if (lane < 8) atomicAdd(&lh[lane], my);
    __syncthreads();
    if (threadIdx.x < 8) gcnt[bk * 8 + threadIdx.x] = lh[threadIdx.x];
}

// ---------------- P0b: scan gcnt -> blkoff + bbase[9]; fused prep constants ----------------
__global__ __launch_bounds__(256) void scan8_kernel(const int* __restrict__ gcnt,
                                                    int* __restrict__ blkoff,
                                                    int* __restrict__ bbase,
                                                    const float* __restrict__ g_logits,
                                                    const float* __restrict__ alpha_logits,
                                                    const int* __restrict__ cell_idx,
                                                    const float* __restrict__ cell_emb,
                                                    const float* __restrict__ W2,
                                                    const float* __restrict__ b2,
                                                    float* __restrict__ gsign,
                                                    float* __restrict__ alph,
                                                    float* __restrict__ cell_dot) {
    __shared__ int psum[8][33];
    int tid = threadIdx.x;
    int s = tid >> 5, g = tid & 31;
    const int per = NB1 / 32;  // 16
    int sum = 0;
    for (int b = g * per; b < (g + 1) * per; ++b) sum += gcnt[b * 8 + s];
    psum[s][g] = sum;
    __syncthreads();
    if (tid < 8) {
        int run = 0;
        for (int i = 0; i < 32; ++i) { int v = psum[tid][i]; psum[tid][i] = run; run += v; }
        psum[tid][32] = run;
    }
    __syncthreads();
    int run = psum[s][g];
    for (int b = g * per; b < (g + 1) * per; ++b) {
        blkoff[b * 8 + s] = run;
        run += gcnt[b * 8 + s];
    }
    if (tid == 0) {
        int acc = 0;
        bbase[0] = 0;
        for (int q = 0; q < 8; ++q) { acc += psum[q][32]; bbase[q + 1] = acc; }
    }
    // fused prep (independent outputs)
    if (tid < 64) {
        if (tid < 6) gsign[tid] = ((tid & 1) ? -1.f : 1.f) * softplusf_(g_logits[tid]);
        if (tid < NSTEPS) alph[tid] = sigmoidf_(alpha_logits[tid]);
        int ci = cell_idx[tid];
        float acc = b2[0];
        for (int hh = 0; hh < HID; ++hh) acc = fmaf(cell_emb[ci * HID + hh], W2[hh], acc);
        cell_dot[tid] = acc;
    }
}

// ---------------- P1: bucket edges by slice; pack {src | dl<<16, coef_f32} ----------------
__global__ __launch_bounds__(256) void bucket_kernel(const int* __restrict__ esrc,
                                                     const int* __restrict__ edst,
                                                     const float* __restrict__ eval,
                                                     const float* __restrict__ gsign,
                                                     const int* __restrict__ blkoff,
                                                     const int* __restrict__ bbase,
                                                     int2* __restrict__ bucket,
                                                     int E, int TE) {
    __shared__ int lcur[8];
    int bk = blockIdx.x;
    int lane = threadIdx.x & 63;
    if (threadIdx.x < 8) lcur[threadIdx.x] = bbase[threadIdx.x] + blkoff[bk * 8 + threadIdx.x];
    __syncthreads();
    int chunk = ((TE + NB1 - 1) / NB1 + 255) & ~255;
    int lo = bk * chunk;
    int hi = min(lo + chunk, TE);
    for (int ii = 0; ii < chunk; ii += 256) {
        int i = lo + ii + (int)threadIdx.x;
        bool act = i < hi;
        int s = -1, meta = 0, cb = 0;
        if (act) {
            int d  = __builtin_nontemporal_load(edst + i);
            int sv = __builtin_nontemporal_load(esrc + i);
            float ev = __builtin_nontemporal_load(eval + i);
            s = slice_of(d);
            int dl = d - s * SLICE_SZ;
            meta = sv | (dl << 16);
            int r = (i >= E) + (i >= 2 * E) + (i >= 3 * E) + (i >= 4 * E) + (i >= 5 * E);
            cb = __float_as_int(gsign[r] * ev);
        }
        int pos = 0;
#pragma unroll
        for (int q = 0; q < 8; ++q) {
            unsigned long long b = __ballot(s == q);
            if (b) {
                int leader = (int)__ffsll(b) - 1;
                int base = 0;
                if (lane == leader) base = atomicAdd(&lcur[q], (int)__popcll(b));
                base = __shfl(base, leader);
                if (s == q) pos = base + (int)__popcll(b & ((1ull << lane) - 1ull));
            }
        }
        if (act) bucket[pos] = make_int2(meta, cb);
    }
}

// ---------------- P2: per-(slice,sub) LDS histogram from the bucket ----------------
__global__ __launch_bounds__(256) void hist2db_kernel(const int2* __restrict__ bucket,
                                                      const int* __restrict__ bbase,
                                                      int* __restrict__ blkcnt) {
    __shared__ int lh[SLICE_SZ];
    int bk = blockIdx.x;
    int slice = bk & (NSLICE - 1);
    int sub = bk >> 3;
    for (int b = threadIdx.x; b < SLICE_SZ; b += 256) lh[b] = 0;
    __syncthreads();
    int lo = bbase[slice];
    int total = bbase[slice + 1] - lo;
    int chunk = ((total + SUBB - 1) / SUBB + 255) & ~255;
    int beg = lo + sub * chunk;
    int end = min(beg + chunk, lo + total);
    const int* mp = (const int*)bucket;
    for (int i = beg + (int)threadIdx.x; i < end; i += 256) {
        int meta = __builtin_nontemporal_load(mp + 2 * (size_t)i);
        atomicAdd(&lh[((unsigned)meta) >> 16], 1);
    }
    __syncthreads();
    int* out = blkcnt + (size_t)(slice * SUBB + sub) * SLICE_SZ;
    for (int b = threadIdx.x; b < SLICE_SZ; b += 256) out[b] = lh[b];
}

// ---------------- P3a: per-bin exclusive prefix across sub-blocks ----------------
__global__ __launch_bounds__(256) void colscan_kernel(int* __restrict__ blkcnt,
                                                      int* __restrict__ counts) {
    int n = blockIdx.x * 256 + threadIdx.x;
    if (n >= N_NODES) return;
    int slice = n / SLICE_SZ, bin = n % SLICE_SZ;
    size_t base = (size_t)slice * SUBB * SLICE_SZ + bin;
    int run = 0;
#pragma unroll 8
    for (int s = 0; s < SUBB; ++s) {
        size_t idx = base + (size_t)s * SLICE_SZ;
        int t = blkcnt[idx];
        blkcnt[idx] = run;
        run += t;
    }
    counts[n] = run;
}

// ---------------- P3b: grp_ptr from counts (rows padded to ×8) ----------------
// Tiled wave-scan: coalesced reads, ~1 KB LDS.
__global__ __launch_bounds__(256) void scan_kernel(const int* __restrict__ counts,
                                                   int* __restrict__ grp_ptr, int n) {
    __shared__ int wsum[4];
    int tid = threadIdx.x;
    int lane = tid & 63, wid = tid >> 6;
    int carry = 0;  // uniform across threads
    for (int base = 0; base < n; base += 256) {
        int i = base + tid;
        int v = (i < n) ? ((counts[i] + 7) >> 3) : 0;  // coalesced
        int x = v;
#pragma unroll
        for (int st = 1; st < 64; st <<= 1) {
            int t = __shfl_up(x, st, 64);
            if (lane >= st) x += t;
        }
        if (lane == 63) wsum[wid] = x;
        __syncthreads();
        int w0 = wsum[0], w1 = wsum[1], w2 = wsum[2], w3 = wsum[3];
        int woff = carry;
        if (wid > 0) woff += w0;
        if (wid > 1) woff += w1;
        if (wid > 2) woff += w2;
        if (i < n) grp_ptr[i] = woff + x - v;  // exclusive
        carry += w0 + w1 + w2 + w3;
        __syncthreads();  // protect wsum before next tile overwrites
    }
    if (tid == 0) grp_ptr[n] = carry;
}

// ---------------- P4: placement into 8-edge groups; fused u-transpose ----------------
// Group g: eg[8g + s] = src | (coef_f16 << 16), s=0..7. Pad slots stay 0.
// NOTE: uh/u_t must NOT alias bucket — transpose blocks run concurrently with
// scatter blocks inside this single launch (R7-R9 aliased them -> race -> fault).
__global__ __launch_bounds__(256) void scatter2b_kernel(const int2* __restrict__ bucket,
                                                        const int* __restrict__ bbase,
                                                        const int* __restrict__ grp_ptr,
                                                        const int* __restrict__ blkcnt,
                                                        unsigned* __restrict__ eg,
                                                        const float* __restrict__ u_raw,
                                                        float* __restrict__ u_t,
                                                        _Float16* __restrict__ uh) {
    __shared__ float smem[64 * 65];  // union: lbase (10 KB) | transpose tile (16.6 KB)
    int bk = blockIdx.x;
    if (bk >= NBLK) {
        // --- transpose section: u_raw [64, N] -> u_t/uh [N, 64] ---
        float(*tile)[65] = (float(*)[65])smem;
        int c0 = (bk - NBLK) * 64;
        int tx = threadIdx.x & 63, ty = threadIdx.x >> 6;
#pragma unroll
        for (int i = 0; i < 16; ++i) {
            int c = c0 + tx;
            tile[ty + i * 4][tx] = (c < N_NODES) ? u_raw[(size_t)(ty + i * 4) * N_NODES + c] : 0.f;
        }
        __syncthreads();
#pragma unroll
        for (int i = 0; i < 16; ++i) {
            int c = c0 + ty + i * 4;
            if (c < N_NODES) {
                float v = tile[tx][ty + i * 4];
                u_t[(size_t)c * 64 + tx] = v;
                uh[(size_t)c * 64 + tx] = (_Float16)v;
            }
        }
        return;
    }
    int* lbase = (int*)smem;
    int slice = bk & (NSLICE - 1);
    int sub = bk >> 3;
    int lo_n = slice * SLICE_SZ;
    const int* boff = blkcnt + (size_t)(slice * SUBB + sub) * SLICE_SZ;
    for (int b = threadIdx.x; b < SLICE_SZ; b += 256)
        lbase[b] = grp_ptr[lo_n + b] * 8 + boff[b];
    __syncthreads();
    int lo = bbase[slice];
    int total = bbase[slice + 1] - lo;
    int chunk = ((total + SUBB - 1) / SUBB + 255) & ~255;
    int beg = lo + sub * chunk;
    int end = min(beg + chunk, lo + total);
    for (int i = beg + (int)threadIdx.x; i < end; i += 256) {
        long long rec = __builtin_nontemporal_load((const long long*)bucket + i);
        int meta = (int)rec;
        float cf = __int_as_float((int)(rec >> 32));
        int pos = atomicAdd(&lbase[((unsigned)meta) >> 16], 1);
        eg[pos] = (unsigned)(meta & 0xFFFF) | ((unsigned)h_as_us((_Float16)cf) << 16);
    }
}

// ---------------- propagation step: 8 edges per gather instruction ----------------
// Wave = 1 node. Lane L: edge slot (L>>3) of each group, batch octet (L&7)*8..+8.
__global__ __launch_bounds__(256) void step_kernel(const _Float16* __restrict__ h_in,
                                                   const float* __restrict__ h0,
                                                   _Float16* __restrict__ h_out,
                                                   float* __restrict__ hF,
                                                   const int* __restrict__ grp_ptr,
                                                   const unsigned* __restrict__ eg,
                                                   const float* __restrict__ alph,
                                                   int k, int last) {
    int lane = threadIdx.x & 63;
    int node = blockIdx.x * 4 + (threadIdx.x >> 6);
    if (node >= N_NODES) return;
    int gb = __builtin_amdgcn_readfirstlane(grp_ptr[node]);
    int ge = __builtin_amdgcn_readfirstlane(grp_ptr[node + 1]);
    int sub8 = lane >> 3;
    const _Float16* hbase = h_in + (lane & 7) * 8;
    float acc[8] = {0.f, 0.f, 0.f, 0.f, 0.f, 0.f, 0.f, 0.f};
    int g = gb;
    for (; g + 2 <= ge; g += 2) {
        unsigned e0 = eg[(size_t)g * 8 + sub8];
        unsigned e1 = eg[(size_t)g * 8 + 8 + sub8];
        h8_t v0 = *(const h8_t*)(hbase + (e0 & 0xFFFFu) * 64);
        h8_t v1 = *(const h8_t*)(hbase + (e1 & 0xFFFFu) * 64);
        float c0 = (float)us_as_h((unsigned short)(e0 >> 16));
        float c1 = (float)us_as_h((unsigned short)(e1 >> 16));
#pragma unroll
        for (int j = 0; j < 8; ++j) acc[j] = fmaf((float)v0[j], c0, acc[j]);
#pragma unroll
        for (int j = 0; j < 8; ++j) acc[j] = fmaf((float)v1[j], c1, acc[j]);
    }
    if (g < ge) {
        unsigned e0 = eg[(size_t)g * 8 + sub8];
        h8_t v0 = *(const h8_t*)(hbase + (e0 & 0xFFFFu) * 64);
        float c0 = (float)us_as_h((unsigned short)(e0 >> 16));
#pragma unroll
        for (int j = 0; j < 8; ++j) acc[j] = fmaf((float)v0[j], c0, acc[j]);
    }
    // reduce edge slots: lanes {c, c+8, ..., c+56} share a batch octet
#pragma unroll
    for (int st = 8; st < 64; st <<= 1) {
#pragma unroll
        for (int j = 0; j < 8; ++j) acc[j] += __shfl_xor(acc[j], st, 64);
    }
    if (lane < 8) {
        float a = alph[k];
        int base = node * 64 + lane * 8;
        float4 h0a = *(const float4*)(h0 + base);
        float4 h0b = *(const float4*)(h0 + base + 4);
        float om = 1.f - a;
        float r0 = fmaf(a, h0a.x, om * acc[0]);
        float r1 = fmaf(a, h0a.y, om * acc[1]);
        float r2 = fmaf(a, h0a.z, om * acc[2]);
        float r3 = fmaf(a, h0a.w, om * acc[3]);
        float r4 = fmaf(a, h0b.x, om * acc[4]);
        float r5 = fmaf(a, h0b.y, om * acc[5]);
        float r6 = fmaf(a, h0b.z, om * acc[6]);
        float r7 = fmaf(a, h0b.w, om * acc[7]);
        if (last) {
            *(float4*)(hF + base)     = make_float4(r0, r1, r2, r3);
            *(float4*)(hF + base + 4) = make_float4(r4, r5, r6, r7);
        } else {
            U4H8 o;
            o.h[0] = (_Float16)r0; o.h[1] = (_Float16)r1;
            o.h[2] = (_Float16)r2; o.h[3] = (_Float16)r3;
            o.h[4] = (_Float16)r4; o.h[5] = (_Float16)r5;
            o.h[6] = (_Float16)r6; o.h[7] = (_Float16)r7;
            *(uint4*)(h_out + base) = o.u;
        }
    }
}

// ---------------- decode (fused LDS transpose of hF [N,64]) ----------------
__global__ __launch_bounds__(256) void decode_kernel(float* __restrict__ y,
                                                     const float* __restrict__ ctl,
                                                     const float* __restrict__ u,
                                                     const float* __restrict__ hF,
                                                     const float* __restrict__ W1,
                                                     const float* __restrict__ b1,
                                                     const float* __restrict__ W2,
                                                     const float* __restrict__ cell_dot) {
    __shared__ float tile[64][65];
    __shared__ float4 pack[HID];
    __shared__ float w2s[HID];
    __shared__ float cds[64];
    if (threadIdx.x < HID) {
        int hh = threadIdx.x;
        pack[hh] = make_float4(W1[0 * HID + hh], W1[1 * HID + hh], W1[2 * HID + hh], b1[hh]);
        w2s[hh] = W2[hh];
        cds[hh] = cell_dot[hh];
    }
    int n0 = blockIdx.x * 64;
    int tx = threadIdx.x & 63, ty = threadIdx.x >> 6;
#pragma unroll
    for (int i = 0; i < 16; ++i) {
        int n = n0 + ty + i * 4;
        tile[ty + i * 4][tx] = (n < N_NODES) ? hF[(size_t)n * 64 + tx] : 0.f;
    }
    __syncthreads();
#pragma unroll
    for (int i = 0; i < 16; ++i) {
        int b = ty + i * 4;
        int n = n0 + tx;
        if (n < N_NODES) {
            size_t idx = (size_t)b * N_NODES + n;
            float xc = ctl[idx], xu = u[idx], xh = tile[tx][b];
            float acc = 0.f;
#pragma unroll 8
            for (int hh = 0; hh < HID; ++hh) {
                float4 p = pack[hh];
                float t = fmaf(xc, p.x, fmaf(xu, p.y, fmaf(xh, p.z, p.w)));
                t = fmaxf(t, 0.f);
                acc = fmaf(t, w2s[hh], acc);
            }
            y[idx] = acc + cds[b];
        }
    }
}

// ---------------- launch ----------------
extern "C" void kernel_launch(void* const* d_in, const int* in_sizes, int n_in,
                              void* d_out, int out_size, void* d_ws, size_t ws_size,
                              hipStream_t stream) {
    const float* ctl          = (const float*)d_in[0];
    const float* u_raw        = (const float*)d_in[1];
    const int*   cell_idx     = (const int*)d_in[2];
    const int*   edge_src     = (const int*)d_in[3];
    const int*   edge_dst     = (const int*)d_in[4];
    const float* edge_val     = (const float*)d_in[5];
    const float* g_logits     = (const float*)d_in[6];
    const float* alpha_logits = (const float*)d_in[7];
    const float* cell_emb     = (const float*)d_in[8];
    const float* W1           = (const float*)d_in[9];
    const float* b1           = (const float*)d_in[10];
    const float* W2           = (const float*)d_in[11];
    const float* b2           = (const float*)d_in[12];
    float* y = (float*)d_out;

    const int TE = in_sizes[3];   // 6 * E
    const int E  = TE / 6;
    const int NB = N_NODES * 64;  // h elements

    char* ws = (char*)d_ws;
    size_t off = 0;
    auto alloc = [&](size_t bytes) -> char* {
        char* p = ws + off;
        off += (bytes + 255) & ~(size_t)255;
        return p;
    };
    int* grp_ptr = (int*)alloc((N_NODES + 1) * sizeof(int));
    int* counts  = (int*)alloc(N_NODES * sizeof(int));
    int* blkcnt  = (int*)alloc((size_t)NSLICE * SUBB * SLICE_SZ * sizeof(int));
    int* gcnt    = (int*)alloc((size_t)NB1 * 8 * sizeof(int));
    int* blkoff  = (int*)alloc((size_t)NB1 * 8 * sizeof(int));
    int* bbase   = (int*)alloc(16 * sizeof(int));
    const size_t MAXG = (size_t)TE / 8 + N_NODES + 8;             // padded group bound
    unsigned* eg = (unsigned*)alloc(MAXG * 8 * sizeof(unsigned)); // 32 B/group
    // DISTINCT buffers (no aliasing): ws is 256 MB, total use ~65 MB
    int2* bucket    = (int2*)alloc((size_t)TE * sizeof(int2));
    _Float16* uh    = (_Float16*)alloc((size_t)NB * 2);
    _Float16* hA    = (_Float16*)alloc((size_t)NB * 2);
    _Float16* hB    = (_Float16*)alloc((size_t)NB * 2);
    float* hF       = (float*)alloc((size_t)NB * 4);
    float* u_t      = (float*)alloc((size_t)NB * sizeof(float));
    float* gsign    = (float*)alloc(8 * sizeof(float));
    float* alph     = (float*)alloc(8 * sizeof(float));
    float* cell_dot = (float*)alloc(64 * sizeof(float));

    // 1. CSR build — edges read once, zero global atomics, XCD-local placement
    count8_kernel<<<NB1, 256, 0, stream>>>(edge_dst, gcnt, TE,
                                           (u4_t*)eg, (long long)(MAXG * 2));
    scan8_kernel<<<1, 256, 0, stream>>>(gcnt, blkoff, bbase, g_logits, alpha_logits,
                                        cell_idx, cell_emb, W2, b2,
                                        gsign, alph, cell_dot);
    bucket_kernel<<<NB1, 256, 0, stream>>>(edge_src, edge_dst, edge_val, gsign,
                                           blkoff, bbase, bucket, E, TE);
    hist2db_kernel<<<NBLK, 256, 0, stream>>>(bucket, bbase, blkcnt);
    colscan_kernel<<<(N_NODES + 255) / 256, 256, 0, stream>>>(blkcnt, counts);
    scan_kernel<<<1, 256, 0, stream>>>(counts, grp_ptr, N_NODES);
    // 2. placement + fused u transpose (u_t fp32, uh f16)
    scatter2b_kernel<<<NBLK + TBLK, 256, 0, stream>>>(bucket, bbase, grp_ptr, blkcnt,
                                                      eg, u_raw, u_t, uh);

    // 3. 6 propagation steps: f16 ping-pong, fp32 final into hF
    const _Float16* hin = uh;
    for (int k = 0; k < NSTEPS; ++k) {
        _Float16* hout = (k & 1) ? hB : hA;
        step_kernel<<<(N_NODES + 3) / 4, 256, 0, stream>>>(hin, u_t, hout, hF, grp_ptr,
                                                           eg, alph, k, k == NSTEPS - 1);
        hin = hout;
    }

    // 4. decode (reads hF [N,64] directly via LDS transpose)
    decode_kernel<<<TBLK, 256, 0, stream>>>(y, ctl, u_raw, hF, W1, b1, W2, cell_dot);
}

// Round 11
// 364.924 us; speedup vs baseline: 1.1236x; 1.1236x over previous
//
#include <hip/hip_runtime.h>

#define N_NODES 20000
#define HID 64
#define NSTEPS 6
#define NSLICE 8
#define SLICE_SZ (N_NODES / NSLICE)  // 2500
#define SUBB 64                      // sub-chunks per slice (phase 2)
#define NBLK (NSLICE * SUBB)         // 512 blocks for hist/scatter
#define TBLK ((N_NODES + 63) / 64)   // 313 transpose blocks (fused into scatter)
#define NB1 512                      // blocks for count/bucket phase
#define CBLK ((N_NODES + 255) / 256) // 79 colscan/scan2 blocks
#define MAGIC 13422                  // floor(d*13422 / 2^25) == d/2500 for d < 20000

typedef _Float16 h8_t __attribute__((ext_vector_type(8)));
typedef unsigned u4_t __attribute__((ext_vector_type(4)));

union U16H { unsigned short u; _Float16 h; };
union U4H8 { uint4 u; _Float16 h[8]; };

__device__ __forceinline__ _Float16 us_as_h(unsigned short s) { U16H u; u.u = s; return u.h; }
__device__ __forceinline__ unsigned short h_as_us(_Float16 h) { U16H u; u.h = h; return u.u; }

__device__ __forceinline__ int slice_of(int d) {
    return (int)(((unsigned)d * (unsigned)MAGIC) >> 25);
}
__device__ __forceinline__ float softplusf_(float x) {
    return (x > 0.f) ? (x + log1pf(expf(-x))) : log1pf(expf(x));
}
__device__ __forceinline__ float sigmoidf_(float x) {
    return 1.f / (1.f + expf(-x));
}

// ---------------- P0: per-(block,slice) edge counts + zero eg groups ----------------
__global__ __launch_bounds__(256) void count8_kernel(const int* __restrict__ edst,
                                                     int* __restrict__ gcnt, int TE,
                                                     u4_t* __restrict__ egq, long long egq_n) {
    // fused: zero the grouped-entry buffer (pad slots must read {src=0,coef=0})
    u4_t z = {0u, 0u, 0u, 0u};
    for (long long i = (long long)blockIdx.x * 256 + threadIdx.x; i < egq_n;
         i += (long long)NB1 * 256)
        __builtin_nontemporal_store(z, egq + i);

    __shared__ int lh[8];
    int bk = blockIdx.x;
    int lane = threadIdx.x & 63;
    if (threadIdx.x < 8) lh[threadIdx.x] = 0;
    __syncthreads();
    int chunk = ((TE + NB1 - 1) / NB1 + 255) & ~255;
    int lo = bk * chunk;
    int hi = min(lo + chunk, TE);
    int my = 0;
    for (int ii = 0; ii < chunk; ii += 256) {
        int i = lo + ii + (int)threadIdx.x;
        bool act = i < hi;
        int s = -1;
        if (act) s = slice_of(__builtin_nontemporal_load(edst + i));
#pragma unroll
        for (int q = 0; q < 8; ++q) {
            unsigned long long b = __ballot(s == q);
            if (lane == q) my += (int)__popcll(b);
        }
    }
    if (lane < 8) atomicAdd(&lh[lane], my);
    __syncthreads();
    if (threadIdx.x < 8) gcnt[bk * 8 + threadIdx.x] = lh[threadIdx.x];
}

// ---------------- P0b: scan gcnt -> blkoff + bbase[9]; fused prep constants ----------------
__global__ __launch_bounds__(256) void scan8_kernel(const int* __restrict__ gcnt,
                                                    int* __restrict__ blkoff,
                                                    int* __restrict__ bbase,
                                                    const float* __restrict__ g_logits,
                                                    const float* __restrict__ alpha_logits,
                                                    const int* __restrict__ cell_idx,
                                                    const float* __restrict__ cell_emb,
                                                    const float* __restrict__ W2,
                                                    const float* __restrict__ b2,
                                                    float* __restrict__ gsign,
                                                    float* __restrict__ alph,
                                                    float* __restrict__ cell_dot) {
    __shared__ int psum[8][33];
    int tid = threadIdx.x;
    int s = tid >> 5, g = tid & 31;
    const int per = NB1 / 32;  // 16
    int sum = 0;
    for (int b = g * per; b < (g + 1) * per; ++b) sum += gcnt[b * 8 + s];
    psum[s][g] = sum;
    __syncthreads();
    if (tid < 8) {
        int run = 0;
        for (int i = 0; i < 32; ++i) { int v = psum[tid][i]; psum[tid][i] = run; run += v; }
        psum[tid][32] = run;
    }
    __syncthreads();
    int run = psum[s][g];
    for (int b = g * per; b < (g + 1) * per; ++b) {
        blkoff[b * 8 + s] = run;
        run += gcnt[b * 8 + s];
    }
    if (tid == 0) {
        int acc = 0;
        bbase[0] = 0;
        for (int q = 0; q < 8; ++q) { acc += psum[q][32]; bbase[q + 1] = acc; }
    }
    // fused prep (independent outputs)
    if (tid < 64) {
        if (tid < 6) gsign[tid] = ((tid & 1) ? -1.f : 1.f) * softplusf_(g_logits[tid]);
        if (tid < NSTEPS) alph[tid] = sigmoidf_(alpha_logits[tid]);
        int ci = cell_idx[tid];
        float acc = b2[0];
        for (int hh = 0; hh < HID; ++hh) acc = fmaf(cell_emb[ci * HID + hh], W2[hh], acc);
        cell_dot[tid] = acc;
    }
}

// ---------------- P1: bucket edges by slice; pack {src | dl<<16, coef_f32} ----------------
__global__ __launch_bounds__(256) void bucket_kernel(const int* __restrict__ esrc,
                                                     const int* __restrict__ edst,
                                                     const float* __restrict__ eval,
                                                     const float* __restrict__ gsign,
                                                     const int* __restrict__ blkoff,
                                                     const int* __restrict__ bbase,
                                                     int2* __restrict__ bucket,
                                                     int E, int TE) {
    __shared__ int lcur[8];
    int bk = blockIdx.x;
    int lane = threadIdx.x & 63;
    if (threadIdx.x < 8) lcur[threadIdx.x] = bbase[threadIdx.x] + blkoff[bk * 8 + threadIdx.x];
    __syncthreads();
    int chunk = ((TE + NB1 - 1) / NB1 + 255) & ~255;
    int lo = bk * chunk;
    int hi = min(lo + chunk, TE);
    for (int ii = 0; ii < chunk; ii += 256) {
        int i = lo + ii + (int)threadIdx.x;
        bool act = i < hi;
        int s = -1, meta = 0, cb = 0;
        if (act) {
            int d  = __builtin_nontemporal_load(edst + i);
            int sv = __builtin_nontemporal_load(esrc + i);
            float ev = __builtin_nontemporal_load(eval + i);
            s = slice_of(d);
            int dl = d - s * SLICE_SZ;
            meta = sv | (dl << 16);
            int r = (i >= E) + (i >= 2 * E) + (i >= 3 * E) + (i >= 4 * E) + (i >= 5 * E);
            cb = __float_as_int(gsign[r] * ev);
        }
        int pos = 0;
#pragma unroll
        for (int q = 0; q < 8; ++q) {
            unsigned long long b = __ballot(s == q);
            if (b) {
                int leader = (int)__ffsll(b) - 1;
                int base = 0;
                if (lane == leader) base = atomicAdd(&lcur[q], (int)__popcll(b));
                base = __shfl(base, leader);
                if (s == q) pos = base + (int)__popcll(b & ((1ull << lane) - 1ull));
            }
        }
        if (act) bucket[pos] = make_int2(meta, cb);
    }
}

// ---------------- P2: per-(slice,sub) LDS histogram from the bucket ----------------
__global__ __launch_bounds__(256) void hist2db_kernel(const int2* __restrict__ bucket,
                                                      const int* __restrict__ bbase,
                                                      int* __restrict__ blkcnt) {
    __shared__ int lh[SLICE_SZ];
    int bk = blockIdx.x;
    int slice = bk & (NSLICE - 1);
    int sub = bk >> 3;
    for (int b = threadIdx.x; b < SLICE_SZ; b += 256) lh[b] = 0;
    __syncthreads();
    int lo = bbase[slice];
    int total = bbase[slice + 1] - lo;
    int chunk = ((total + SUBB - 1) / SUBB + 255) & ~255;
    int beg = lo + sub * chunk;
    int end = min(beg + chunk, lo + total);
    const int* mp = (const int*)bucket;
    for (int i = beg + (int)threadIdx.x; i < end; i += 256) {
        int meta = __builtin_nontemporal_load(mp + 2 * (size_t)i);
        atomicAdd(&lh[((unsigned)meta) >> 16], 1);
    }
    __syncthreads();
    int* out = blkcnt + (size_t)(slice * SUBB + sub) * SLICE_SZ;
    for (int b = threadIdx.x; b < SLICE_SZ; b += 256) out[b] = lh[b];
}

// ---------------- P3a: per-bin prefix across sub-blocks + per-block group sums ----------------
__global__ __launch_bounds__(256) void colscan_kernel(int* __restrict__ blkcnt,
                                                      int* __restrict__ counts,
                                                      int* __restrict__ blksum) {
    int n = blockIdx.x * 256 + threadIdx.x;
    int run = 0;
    if (n < N_NODES) {
        int slice = n / SLICE_SZ, bin = n % SLICE_SZ;
        size_t base = (size_t)slice * SUBB * SLICE_SZ + bin;
#pragma unroll 8
        for (int s = 0; s < SUBB; ++s) {
            size_t idx = base + (size_t)s * SLICE_SZ;
            int t = blkcnt[idx];
            blkcnt[idx] = run;
            run += t;
        }
        counts[n] = run;
    }
    // fused: block sum of padded group counts -> blksum[blockIdx.x]
    int g = (n < N_NODES) ? ((run + 7) >> 3) : 0;
#pragma unroll
    for (int st = 1; st < 64; st <<= 1) g += __shfl_xor(g, st, 64);
    __shared__ int wsum[4];
    if ((threadIdx.x & 63) == 0) wsum[threadIdx.x >> 6] = g;
    __syncthreads();
    if (threadIdx.x == 0) blksum[blockIdx.x] = wsum[0] + wsum[1] + wsum[2] + wsum[3];
}

// ---------------- P3b: parallel scan -> grp_ptr (79 blocks, no serial chain) ----------------
__global__ __launch_bounds__(256) void scan2_kernel(const int* __restrict__ counts,
                                                    const int* __restrict__ blksum,
                                                    int* __restrict__ grp_ptr, int n) {
    int b = blockIdx.x;
    int tid = threadIdx.x, lane = tid & 63, wid = tid >> 6;
    int i = b * 256 + tid;
    int v = (i < n) ? ((counts[i] + 7) >> 3) : 0;
    int x = v;
#pragma unroll
    for (int st = 1; st < 64; st <<= 1) {
        int t = __shfl_up(x, st, 64);
        if (lane >= st) x += t;
    }
    __shared__ int wsum[4];
    if (lane == 63) wsum[wid] = x;
    // global offset: sum of blksum[l < b], redundant per wave (CBLK=79 < 128)
    int s = ((lane < b) ? blksum[lane] : 0) +
            ((lane + 64 < b) ? blksum[lane + 64] : 0);
#pragma unroll
    for (int st = 1; st < 64; st <<= 1) s += __shfl_xor(s, st, 64);
    __syncthreads();
    int woff = s;
    if (wid > 0) woff += wsum[0];
    if (wid > 1) woff += wsum[1];
    if (wid > 2) woff += wsum[2];
    int off = woff + x - v;  // exclusive
    if (i < n) grp_ptr[i] = off;
    if (i == n - 1) grp_ptr[n] = off + v;
}

// ---------------- P4: placement into 8-edge groups; fused u-transpose ----------------
// Group g: eg[8g + s] = src | (coef_f16 << 16), s=0..7. Pad slots stay 0.
// NOTE: uh/u_t must NOT alias bucket — transpose blocks run concurrently with
// scatter blocks inside this single launch.
__global__ __launch_bounds__(256) void scatter2b_kernel(const int2* __restrict__ bucket,
                                                        const int* __restrict__ bbase,
                                                        const int* __restrict__ grp_ptr,
                                                        const int* __restrict__ blkcnt,
                                                        unsigned* __restrict__ eg,
                                                        const float* __restrict__ u_raw,
                                                        float* __restrict__ u_t,
                                                        _Float16* __restrict__ uh) {
    __shared__ float smem[64 * 65];  // union: lbase (10 KB) | transpose tile (16.6 KB)
    int bk = blockIdx.x;
    if (bk >= NBLK) {
        // --- transpose section: u_raw [64, N] -> u_t/uh [N, 64] ---
        float(*tile)[65] = (float(*)[65])smem;
        int c0 = (bk - NBLK) * 64;
        int tx = threadIdx.x & 63, ty = threadIdx.x >> 6;
#pragma unroll
        for (int i = 0; i < 16; ++i) {
            int c = c0 + tx;
            tile[ty + i * 4][tx] = (c < N_NODES) ? u_raw[(size_t)(ty + i * 4) * N_NODES + c] : 0.f;
        }
        __syncthreads();
#pragma unroll
        for (int i = 0; i < 16; ++i) {
            int c = c0 + ty + i * 4;
            if (c < N_NODES) {
                float v = tile[tx][ty + i * 4];
                u_t[(size_t)c * 64 + tx] = v;
                uh[(size_t)c * 64 + tx] = (_Float16)v;
            }
        }
        return;
    }
    int* lbase = (int*)smem;
    int slice = bk & (NSLICE - 1);
    int sub = bk >> 3;
    int lo_n = slice * SLICE_SZ;
    const int* boff = blkcnt + (size_t)(slice * SUBB + sub) * SLICE_SZ;
    for (int b = threadIdx.x; b < SLICE_SZ; b += 256)
        lbase[b] = grp_ptr[lo_n + b] * 8 + boff[b];
    __syncthreads();
    int lo = bbase[slice];
    int total = bbase[slice + 1] - lo;
    int chunk = ((total + SUBB - 1) / SUBB + 255) & ~255;
    int beg = lo + sub * chunk;
    int end = min(beg + chunk, lo + total);
    for (int i = beg + (int)threadIdx.x; i < end; i += 256) {
        long long rec = __builtin_nontemporal_load((const long long*)bucket + i);
        int meta = (int)rec;
        float cf = __int_as_float((int)(rec >> 32));
        int pos = atomicAdd(&lbase[((unsigned)meta) >> 16], 1);
        eg[pos] = (unsigned)(meta & 0xFFFF) | ((unsigned)h_as_us((_Float16)cf) << 16);
    }
}

// ---------------- propagation step: 8 edges per gather instruction ----------------
// Wave = 1 node. Lane L: edge slot (L>>3) of each group, batch octet (L&7)*8..+8.
__global__ __launch_bounds__(256) void step_kernel(const _Float16* __restrict__ h_in,
                                                   const float* __restrict__ h0,
                                                   _Float16* __restrict__ h_out,
                                                   float* __restrict__ hF,
                                                   const int* __restrict__ grp_ptr,
                                                   const unsigned* __restrict__ eg,
                                                   const float* __restrict__ alph,
                                                   int k, int last) {
    int lane = threadIdx.x & 63;
    int node = blockIdx.x * 4 + (threadIdx.x >> 6);
    if (node >= N_NODES) return;
    int gb = __builtin_amdgcn_readfirstlane(grp_ptr[node]);
    int ge = __builtin_amdgcn_readfirstlane(grp_ptr[node + 1]);
    int sub8 = lane >> 3;
    const _Float16* hbase = h_in + (lane & 7) * 8;
    float acc[8] = {0.f, 0.f, 0.f, 0.f, 0.f, 0.f, 0.f, 0.f};
    int g = gb;
    for (; g + 2 <= ge; g += 2) {
        unsigned e0 = eg[(size_t)g * 8 + sub8];
        unsigned e1 = eg[(size_t)g * 8 + 8 + sub8];
        h8_t v0 = *(const h8_t*)(hbase + (e0 & 0xFFFFu) * 64);
        h8_t v1 = *(const h8_t*)(hbase + (e1 & 0xFFFFu) * 64);
        float c0 = (float)us_as_h((unsigned short)(e0 >> 16));
        float c1 = (float)us_as_h((unsigned short)(e1 >> 16));
#pragma unroll
        for (int j = 0; j < 8; ++j) acc[j] = fmaf((float)v0[j], c0, acc[j]);
#pragma unroll
        for (int j = 0; j < 8; ++j) acc[j] = fmaf((float)v1[j], c1, acc[j]);
    }
    if (g < ge) {
        unsigned e0 = eg[(size_t)g * 8 + sub8];
        h8_t v0 = *(const h8_t*)(hbase + (e0 & 0xFFFFu) * 64);
        float c0 = (float)us_as_h((unsigned short)(e0 >> 16));
#pragma unroll
        for (int j = 0; j < 8; ++j) acc[j] = fmaf((float)v0[j], c0, acc[j]);
    }
    // reduce edge slots: lanes {c, c+8, ..., c+56} share a batch octet
#pragma unroll
    for (int st = 8; st < 64; st <<= 1) {
#pragma unroll
        for (int j = 0; j < 8; ++j) acc[j] += __shfl_xor(acc[j], st, 64);
    }
    if (lane < 8) {
        float a = alph[k];
        int base = node * 64 + lane * 8;
        float4 h0a = *(const float4*)(h0 + base);
        float4 h0b = *(const float4*)(h0 + base + 4);
        float om = 1.f - a;
        float r0 = fmaf(a, h0a.x, om * acc[0]);
        float r1 = fmaf(a, h0a.y, om * acc[1]);
        float r2 = fmaf(a, h0a.z, om * acc[2]);
        float r3 = fmaf(a, h0a.w, om * acc[3]);
        float r4 = fmaf(a, h0b.x, om * acc[4]);
        float r5 = fmaf(a, h0b.y, om * acc[5]);
        float r6 = fmaf(a, h0b.z, om * acc[6]);
        float r7 = fmaf(a, h0b.w, om * acc[7]);
        if (last) {
            *(float4*)(hF + base)     = make_float4(r0, r1, r2, r3);
            *(float4*)(hF + base + 4) = make_float4(r4, r5, r6, r7);
        } else {
            U4H8 o;
            o.h[0] = (_Float16)r0; o.h[1] = (_Float16)r1;
            o.h[2] = (_Float16)r2; o.h[3] = (_Float16)r3;
            o.h[4] = (_Float16)r4; o.h[5] = (_Float16)r5;
            o.h[6] = (_Float16)r6; o.h[7] = (_Float16)r7;
            *(uint4*)(h_out + base) = o.u;
        }
    }
}

// ---------------- decode (fused LDS transpose of hF [N,64]) ----------------
__global__ __launch_bounds__(256) void decode_kernel(float* __restrict__ y,
                                                     const float* __restrict__ ctl,
                                                     const float* __restrict__ u,
                                                     const float* __restrict__ hF,
                                                     const float* __restrict__ W1,
                                                     const float* __restrict__ b1,
                                                     const float* __restrict__ W2,
                                                     const float* __restrict__ cell_dot) {
    __shared__ float tile[64][65];
    __shared__ float4 pack[HID];
    __shared__ float w2s[HID];
    __shared__ float cds[64];
    if (threadIdx.x < HID) {
        int hh = threadIdx.x;
        pack[hh] = make_float4(W1[0 * HID + hh], W1[1 * HID + hh], W1[2 * HID + hh], b1[hh]);
        w2s[hh] = W2[hh];
        cds[hh] = cell_dot[hh];
    }
    int n0 = blockIdx.x * 64;
    int tx = threadIdx.x & 63, ty = threadIdx.x >> 6;
#pragma unroll
    for (int i = 0; i < 16; ++i) {
        int n = n0 + ty + i * 4;
        tile[ty + i * 4][tx] = (n < N_NODES) ? hF[(size_t)n * 64 + tx] : 0.f;
    }
    __syncthreads();
#pragma unroll
    for (int i = 0; i < 16; ++i) {
        int b = ty + i * 4;
        int n = n0 + tx;
        if (n < N_NODES) {
            size_t idx = (size_t)b * N_NODES + n;
            float xc = ctl[idx], xu = u[idx], xh = tile[tx][b];
            float acc = 0.f;
#pragma unroll 8
            for (int hh = 0; hh < HID; ++hh) {
                float4 p = pack[hh];
                float t = fmaf(xc, p.x, fmaf(xu, p.y, fmaf(xh, p.z, p.w)));
                t = fmaxf(t, 0.f);
                acc = fmaf(t, w2s[hh], acc);
            }
            y[idx] = acc + cds[b];
        }
    }
}

// ---------------- launch ----------------
extern "C" void kernel_launch(void* const* d_in, const int* in_sizes, int n_in,
                              void* d_out, int out_size, void* d_ws, size_t ws_size,
                              hipStream_t stream) {
    const float* ctl          = (const float*)d_in[0];
    const float* u_raw        = (const float*)d_in[1];
    const int*   cell_idx     = (const int*)d_in[2];
    const int*   edge_src     = (const int*)d_in[3];
    const int*   edge_dst     = (const int*)d_in[4];
    const float* edge_val     = (const float*)d_in[5];
    const float* g_logits     = (const float*)d_in[6];
    const float* alpha_logits = (const float*)d_in[7];
    const float* cell_emb     = (const float*)d_in[8];
    const float* W1           = (const float*)d_in[9];
    const float* b1           = (const float*)d_in[10];
    const float* W2           = (const float*)d_in[11];
    const float* b2           = (const float*)d_in[12];
    float* y = (float*)d_out;

    const int TE = in_sizes[3];   // 6 * E
    const int E  = TE / 6;
    const int NB = N_NODES * 64;  // h elements

    char* ws = (char*)d_ws;
    size_t off = 0;
    auto alloc = [&](size_t bytes) -> char* {
        char* p = ws + off;
        off += (bytes + 255) & ~(size_t)255;
        return p;
    };
    int* grp_ptr = (int*)alloc((N_NODES + 1) * sizeof(int));
    int* counts  = (int*)alloc(N_NODES * sizeof(int));
    int* blksum  = (int*)alloc(CBLK * sizeof(int));
    int* blkcnt  = (int*)alloc((size_t)NSLICE * SUBB * SLICE_SZ * sizeof(int));
    int* gcnt    = (int*)alloc((size_t)NB1 * 8 * sizeof(int));
    int* blkoff  = (int*)alloc((size_t)NB1 * 8 * sizeof(int));
    int* bbase   = (int*)alloc(16 * sizeof(int));
    const size_t MAXG = (size_t)TE / 8 + N_NODES + 8;             // padded group bound
    unsigned* eg = (unsigned*)alloc(MAXG * 8 * sizeof(unsigned)); // 32 B/group
    // DISTINCT buffers (no aliasing): ws is 256 MB, total use ~65 MB
    int2* bucket    = (int2*)alloc((size_t)TE * sizeof(int2));
    _Float16* uh    = (_Float16*)alloc((size_t)NB * 2);
    _Float16* hA    = (_Float16*)alloc((size_t)NB * 2);
    _Float16* hB    = (_Float16*)alloc((size_t)NB * 2);
    float* hF       = (float*)alloc((size_t)NB * 4);
    float* u_t      = (float*)alloc((size_t)NB * sizeof(float));
    float* gsign    = (float*)alloc(8 * sizeof(float));
    float* alph     = (float*)alloc(8 * sizeof(float));
    float* cell_dot = (float*)alloc(64 * sizeof(float));

    // 1. CSR build — edges read once, zero global atomics, XCD-local placement
    count8_kernel<<<NB1, 256, 0, stream>>>(edge_dst, gcnt, TE,
                                           (u4_t*)eg, (long long)(MAXG * 2));
    scan8_kernel<<<1, 256, 0, stream>>>(gcnt, blkoff, bbase, g_logits, alpha_logits,
                                        cell_idx, cell_emb, W2, b2,
                                        gsign, alph, cell_dot);
    bucket_kernel<<<NB1, 256, 0, stream>>>(edge_src, edge_dst, edge_val, gsign,
                                           blkoff, bbase, bucket, E, TE);
    hist2db_kernel<<<NBLK, 256, 0, stream>>>(bucket, bbase, blkcnt);
    colscan_kernel<<<CBLK, 256, 0, stream>>>(blkcnt, counts, blksum);
    scan2_kernel<<<CBLK, 256, 0, stream>>>(counts, blksum, grp_ptr, N_NODES);
    // 2. placement + fused u transpose (u_t fp32, uh f16)
    scatter2b_kernel<<<NBLK + TBLK, 256, 0, stream>>>(bucket, bbase, grp_ptr, blkcnt,
                                                      eg, u_raw, u_t, uh);

    // 3. 6 propagation steps: f16 ping-pong, fp32 final into hF
    const _Float16* hin = uh;
    for (int k = 0; k < NSTEPS; ++k) {
        _Float16* hout = (k & 1) ? hB : hA;
        step_kernel<<<(N_NODES + 3) / 4, 256, 0, stream>>>(hin, u_t, hout, hF, grp_ptr,
                                                           eg, alph, k, k == NSTEPS - 1);
        hin = hout;
    }

    // 4. decode (reads hF [N,64] directly via LDS transpose)
    decode_kernel<<<TBLK, 256, 0, stream>>>(y, ctl, u_raw, hF, W1, b1, W2, cell_dot);
}

// Round 12
// 342.492 us; speedup vs baseline: 1.1972x; 1.0655x over previous
//
#include <hip/hip_runtime.h>

#define N_NODES 20000
#define HID 64
#define NSTEPS 6
#define NSLICE 8
#define SLICE_SZ (N_NODES / NSLICE)  // 2500
#define SUBB 64                      // sub-chunks per slice (phase 2)
#define NBLK (NSLICE * SUBB)         // 512 blocks for hist/scatter
#define TBLK ((N_NODES + 63) / 64)   // 313 transpose blocks (fused into scatter)
#define NB1 512                      // blocks for count/bucket phase
#define CBLK ((N_NODES + 255) / 256) // 79 colscan/scan2 blocks
#define MAGIC 13422                  // floor(d*13422 / 2^25) == d/2500 for d < 20000

typedef _Float16 h8_t __attribute__((ext_vector_type(8)));
typedef unsigned u4_t __attribute__((ext_vector_type(4)));

union U16H { unsigned short u; _Float16 h; };
union U4H8 { uint4 u; _Float16 h[8]; };

__device__ __forceinline__ _Float16 us_as_h(unsigned short s) { U16H u; u.u = s; return u.h; }
__device__ __forceinline__ unsigned short h_as_us(_Float16 h) { U16H u; u.h = h; return u.u; }

__device__ __forceinline__ int slice_of(int d) {
    return (int)(((unsigned)d * (unsigned)MAGIC) >> 25);
}
__device__ __forceinline__ float softplusf_(float x) {
    return (x > 0.f) ? (x + log1pf(expf(-x))) : log1pf(expf(x));
}
__device__ __forceinline__ float sigmoidf_(float x) {
    return 1.f / (1.f + expf(-x));
}

// ---------------- P0: per-(block,slice) edge counts + zero eg groups ----------------
__global__ __launch_bounds__(256) void count8_kernel(const int* __restrict__ edst,
                                                     int* __restrict__ gcnt, int TE,
                                                     u4_t* __restrict__ egq, long long egq_n) {
    // fused: zero the grouped-entry buffer (pad slots must read {src=0,coef=0})
    u4_t z = {0u, 0u, 0u, 0u};
    for (long long i = (long long)blockIdx.x * 256 + threadIdx.x; i < egq_n;
         i += (long long)NB1 * 256)
        __builtin_nontemporal_store(z, egq + i);

    __shared__ int lh[8];
    int bk = blockIdx.x;
    int lane = threadIdx.x & 63;
    if (threadIdx.x < 8) lh[threadIdx.x] = 0;
    __syncthreads();
    int chunk = ((TE + NB1 - 1) / NB1 + 255) & ~255;
    int lo = bk * chunk;
    int hi = min(lo + chunk, TE);
    int my = 0;
    for (int ii = 0; ii < chunk; ii += 256) {
        int i = lo + ii + (int)threadIdx.x;
        bool act = i < hi;
        int s = -1;
        if (act) s = slice_of(__builtin_nontemporal_load(edst + i));
#pragma unroll
        for (int q = 0; q < 8; ++q) {
            unsigned long long b = __ballot(s == q);
            if (lane == q) my += (int)__popcll(b);
        }
    }
    if (lane < 8) atomicAdd(&lh[lane], my);
    __syncthreads();
    if (threadIdx.x < 8) gcnt[bk * 8 + threadIdx.x] = lh[threadIdx.x];
}

// ---------------- P0b: scan gcnt -> blkoff + bbase[9]; fused prep constants ----------------
__global__ __launch_bounds__(256) void scan8_kernel(const int* __restrict__ gcnt,
                                                    int* __restrict__ blkoff,
                                                    int* __restrict__ bbase,
                                                    const float* __restrict__ g_logits,
                                                    const float* __restrict__ alpha_logits,
                                                    const int* __restrict__ cell_idx,
                                                    const float* __restrict__ cell_emb,
                                                    const float* __restrict__ W2,
                                                    const float* __restrict__ b2,
                                                    float* __restrict__ gsign,
                                                    float* __restrict__ alph,
                                                    float* __restrict__ cell_dot) {
    __shared__ int psum[8][33];
    int tid = threadIdx.x;
    int s = tid >> 5, g = tid & 31;
    const int per = NB1 / 32;  // 16
    int sum = 0;
    for (int b = g * per; b < (g + 1) * per; ++b) sum += gcnt[b * 8 + s];
    psum[s][g] = sum;
    __syncthreads();
    if (tid < 8) {
        int run = 0;
        for (int i = 0; i < 32; ++i) { int v = psum[tid][i]; psum[tid][i] = run; run += v; }
        psum[tid][32] = run;
    }
    __syncthreads();
    int run = psum[s][g];
    for (int b = g * per; b < (g + 1) * per; ++b) {
        blkoff[b * 8 + s] = run;
        run += gcnt[b * 8 + s];
    }
    if (tid == 0) {
        int acc = 0;
        bbase[0] = 0;
        for (int q = 0; q < 8; ++q) { acc += psum[q][32]; bbase[q + 1] = acc; }
    }
    // fused prep (independent outputs)
    if (tid < 64) {
        if (tid < 6) gsign[tid] = ((tid & 1) ? -1.f : 1.f) * softplusf_(g_logits[tid]);
        if (tid < NSTEPS) alph[tid] = sigmoidf_(alpha_logits[tid]);
        int ci = cell_idx[tid];
        float acc = b2[0];
        for (int hh = 0; hh < HID; ++hh) acc = fmaf(cell_emb[ci * HID + hh], W2[hh], acc);
        cell_dot[tid] = acc;
    }
}

// ---------------- P1: bucket edges by slice; pack {src | dl<<16, coef_f32} ----------------
__global__ __launch_bounds__(256) void bucket_kernel(const int* __restrict__ esrc,
                                                     const int* __restrict__ edst,
                                                     const float* __restrict__ eval,
                                                     const float* __restrict__ gsign,
                                                     const int* __restrict__ blkoff,
                                                     const int* __restrict__ bbase,
                                                     int2* __restrict__ bucket,
                                                     int E, int TE) {
    __shared__ int lcur[8];
    int bk = blockIdx.x;
    int lane = threadIdx.x & 63;
    if (threadIdx.x < 8) lcur[threadIdx.x] = bbase[threadIdx.x] + blkoff[bk * 8 + threadIdx.x];
    __syncthreads();
    int chunk = ((TE + NB1 - 1) / NB1 + 255) & ~255;
    int lo = bk * chunk;
    int hi = min(lo + chunk, TE);
    for (int ii = 0; ii < chunk; ii += 256) {
        int i = lo + ii + (int)threadIdx.x;
        bool act = i < hi;
        int s = -1, meta = 0, cb = 0;
        if (act) {
            int d  = __builtin_nontemporal_load(edst + i);
            int sv = __builtin_nontemporal_load(esrc + i);
            float ev = __builtin_nontemporal_load(eval + i);
            s = slice_of(d);
            int dl = d - s * SLICE_SZ;
            meta = sv | (dl << 16);
            int r = (i >= E) + (i >= 2 * E) + (i >= 3 * E) + (i >= 4 * E) + (i >= 5 * E);
            cb = __float_as_int(gsign[r] * ev);
        }
        int pos = 0;
#pragma unroll
        for (int q = 0; q < 8; ++q) {
            unsigned long long b = __ballot(s == q);
            if (b) {
                int leader = (int)__ffsll(b) - 1;
                int base = 0;
                if (lane == leader) base = atomicAdd(&lcur[q], (int)__popcll(b));
                base = __shfl(base, leader);
                if (s == q) pos = base + (int)__popcll(b & ((1ull << lane) - 1ull));
            }
        }
        if (act) bucket[pos] = make_int2(meta, cb);
    }
}

// ---------------- P2: per-(slice,sub) LDS histogram from the bucket ----------------
__global__ __launch_bounds__(256) void hist2db_kernel(const int2* __restrict__ bucket,
                                                      const int* __restrict__ bbase,
                                                      int* __restrict__ blkcnt) {
    __shared__ int lh[SLICE_SZ];
    int bk = blockIdx.x;
    int slice = bk & (NSLICE - 1);
    int sub = bk >> 3;
    for (int b = threadIdx.x; b < SLICE_SZ; b += 256) lh[b] = 0;
    __syncthreads();
    int lo = bbase[slice];
    int total = bbase[slice + 1] - lo;
    int chunk = ((total + SUBB - 1) / SUBB + 255) & ~255;
    int beg = lo + sub * chunk;
    int end = min(beg + chunk, lo + total);
    const int* mp = (const int*)bucket;
    for (int i = beg + (int)threadIdx.x; i < end; i += 256) {
        int meta = __builtin_nontemporal_load(mp + 2 * (size_t)i);
        atomicAdd(&lh[((unsigned)meta) >> 16], 1);
    }
    __syncthreads();
    int* out = blkcnt + (size_t)(slice * SUBB + sub) * SLICE_SZ;
    for (int b = threadIdx.x; b < SLICE_SZ; b += 256) out[b] = lh[b];
}

// ---------------- P3a: per-bin prefix across sub-blocks + per-block group sums ----------------
__global__ __launch_bounds__(256) void colscan_kernel(int* __restrict__ blkcnt,
                                                      int* __restrict__ counts,
                                                      int* __restrict__ blksum) {
    int n = blockIdx.x * 256 + threadIdx.x;
    int run = 0;
    if (n < N_NODES) {
        int slice = n / SLICE_SZ, bin = n % SLICE_SZ;
        size_t base = (size_t)slice * SUBB * SLICE_SZ + bin;
#pragma unroll 8
        for (int s = 0; s < SUBB; ++s) {
            size_t idx = base + (size_t)s * SLICE_SZ;
            int t = blkcnt[idx];
            blkcnt[idx] = run;
            run += t;
        }
        counts[n] = run;
    }
    // fused: block sum of padded group counts -> blksum[blockIdx.x]
    int g = (n < N_NODES) ? ((run + 7) >> 3) : 0;
#pragma unroll
    for (int st = 1; st < 64; st <<= 1) g += __shfl_xor(g, st, 64);
    __shared__ int wsum[4];
    if ((threadIdx.x & 63) == 0) wsum[threadIdx.x >> 6] = g;
    __syncthreads();
    if (threadIdx.x == 0) blksum[blockIdx.x] = wsum[0] + wsum[1] + wsum[2] + wsum[3];
}

// ---------------- P3b: parallel scan -> grp_ptr (79 blocks, no serial chain) ----------------
__global__ __launch_bounds__(256) void scan2_kernel(const int* __restrict__ counts,
                                                    const int* __restrict__ blksum,
                                                    int* __restrict__ grp_ptr, int n) {
    int b = blockIdx.x;
    int tid = threadIdx.x, lane = tid & 63, wid = tid >> 6;
    int i = b * 256 + tid;
    int v = (i < n) ? ((counts[i] + 7) >> 3) : 0;
    int x = v;
#pragma unroll
    for (int st = 1; st < 64; st <<= 1) {
        int t = __shfl_up(x, st, 64);
        if (lane >= st) x += t;
    }
    __shared__ int wsum[4];
    if (lane == 63) wsum[wid] = x;
    // global offset: sum of blksum[l < b], redundant per wave (CBLK=79 < 128)
    int s = ((lane < b) ? blksum[lane] : 0) +
            ((lane + 64 < b) ? blksum[lane + 64] : 0);
#pragma unroll
    for (int st = 1; st < 64; st <<= 1) s += __shfl_xor(s, st, 64);
    __syncthreads();
    int woff = s;
    if (wid > 0) woff += wsum[0];
    if (wid > 1) woff += wsum[1];
    if (wid > 2) woff += wsum[2];
    int off = woff + x - v;  // exclusive
    if (i < n) grp_ptr[i] = off;
    if (i == n - 1) grp_ptr[n] = off + v;
}

// ---------------- P4: placement into 8-edge groups; fused u-transpose ----------------
// Group g: eg[8g + s] = src | (coef_f16 << 16), s=0..7. Pad slots stay 0.
// NOTE: uh/u_t must NOT alias bucket — transpose blocks run concurrently with
// scatter blocks inside this single launch.
__global__ __launch_bounds__(256) void scatter2b_kernel(const int2* __restrict__ bucket,
                                                        const int* __restrict__ bbase,
                                                        const int* __restrict__ grp_ptr,
                                                        const int* __restrict__ blkcnt,
                                                        unsigned* __restrict__ eg,
                                                        const float* __restrict__ u_raw,
                                                        float* __restrict__ u_t,
                                                        _Float16* __restrict__ uh) {
    __shared__ float smem[64 * 65];  // union: lbase (10 KB) | transpose tile (16.6 KB)
    int bk = blockIdx.x;
    if (bk >= NBLK) {
        // --- transpose section: u_raw [64, N] -> u_t/uh [N, 64] ---
        float(*tile)[65] = (float(*)[65])smem;
        int c0 = (bk - NBLK) * 64;
        int tx = threadIdx.x & 63, ty = threadIdx.x >> 6;
#pragma unroll
        for (int i = 0; i < 16; ++i) {
            int c = c0 + tx;
            tile[ty + i * 4][tx] = (c < N_NODES) ? u_raw[(size_t)(ty + i * 4) * N_NODES + c] : 0.f;
        }
        __syncthreads();
#pragma unroll
        for (int i = 0; i < 16; ++i) {
            int c = c0 + ty + i * 4;
            if (c < N_NODES) {
                float v = tile[tx][ty + i * 4];
                u_t[(size_t)c * 64 + tx] = v;
                uh[(size_t)c * 64 + tx] = (_Float16)v;
            }
        }
        return;
    }
    int* lbase = (int*)smem;
    int slice = bk & (NSLICE - 1);
    int sub = bk >> 3;
    int lo_n = slice * SLICE_SZ;
    const int* boff = blkcnt + (size_t)(slice * SUBB + sub) * SLICE_SZ;
    for (int b = threadIdx.x; b < SLICE_SZ; b += 256)
        lbase[b] = grp_ptr[lo_n + b] * 8 + boff[b];
    __syncthreads();
    int lo = bbase[slice];
    int total = bbase[slice + 1] - lo;
    int chunk = ((total + SUBB - 1) / SUBB + 255) & ~255;
    int beg = lo + sub * chunk;
    int end = min(beg + chunk, lo + total);
    for (int i = beg + (int)threadIdx.x; i < end; i += 256) {
        long long rec = __builtin_nontemporal_load((const long long*)bucket + i);
        int meta = (int)rec;
        float cf = __int_as_float((int)(rec >> 32));
        int pos = atomicAdd(&lbase[((unsigned)meta) >> 16], 1);
        eg[pos] = (unsigned)(meta & 0xFFFF) | ((unsigned)h_as_us((_Float16)cf) << 16);
    }
}

// ---------------- propagation step: 8 edges/gather, 4-group software pipeline ----------------
// Wave = 1 node. Lane L: edge slot (L>>3) of each group, batch octet (L&7)*8..+8.
// Pipeline: gathers for quad i issue first, then eg loads for quad i+1 (independent,
// overlap gather latency), then FMAs (wait on gathers).
__global__ __launch_bounds__(256) void step_kernel(const _Float16* __restrict__ h_in,
                                                   const float* __restrict__ h0,
                                                   _Float16* __restrict__ h_out,
                                                   float* __restrict__ hF,
                                                   const int* __restrict__ grp_ptr,
                                                   const unsigned* __restrict__ eg,
                                                   const float* __restrict__ alph,
                                                   int k, int last) {
    int lane = threadIdx.x & 63;
    int node = blockIdx.x * 4 + (threadIdx.x >> 6);
    if (node >= N_NODES) return;
    int gb = __builtin_amdgcn_readfirstlane(grp_ptr[node]);
    int ge = __builtin_amdgcn_readfirstlane(grp_ptr[node + 1]);
    int sub8 = lane >> 3;
    const _Float16* hbase = h_in + (lane & 7) * 8;
    const unsigned* ep = eg + sub8;
    float acc[8] = {0.f, 0.f, 0.f, 0.f, 0.f, 0.f, 0.f, 0.f};
    int g = gb;
    unsigned e0, e1, e2, e3;
    if (g + 4 <= ge) {
        e0 = ep[(size_t)g * 8];
        e1 = ep[(size_t)g * 8 + 8];
        e2 = ep[(size_t)g * 8 + 16];
        e3 = ep[(size_t)g * 8 + 24];
    }
    for (; g + 8 <= ge; g += 4) {
        // gathers for current quad
        h8_t v0 = *(const h8_t*)(hbase + (e0 & 0xFFFFu) * 64);
        h8_t v1 = *(const h8_t*)(hbase + (e1 & 0xFFFFu) * 64);
        h8_t v2 = *(const h8_t*)(hbase + (e2 & 0xFFFFu) * 64);
        h8_t v3 = *(const h8_t*)(hbase + (e3 & 0xFFFFu) * 64);
        // prefetch next quad's entries (independent of gathers)
        unsigned f0 = ep[(size_t)(g + 4) * 8];
        unsigned f1 = ep[(size_t)(g + 4) * 8 + 8];
        unsigned f2 = ep[(size_t)(g + 4) * 8 + 16];
        unsigned f3 = ep[(size_t)(g + 4) * 8 + 24];
        float c0 = (float)us_as_h((unsigned short)(e0 >> 16));
        float c1 = (float)us_as_h((unsigned short)(e1 >> 16));
        float c2 = (float)us_as_h((unsigned short)(e2 >> 16));
        float c3 = (float)us_as_h((unsigned short)(e3 >> 16));
#pragma unroll
        for (int j = 0; j < 8; ++j) acc[j] = fmaf((float)v0[j], c0, acc[j]);
#pragma unroll
        for (int j = 0; j < 8; ++j) acc[j] = fmaf((float)v1[j], c1, acc[j]);
#pragma unroll
        for (int j = 0; j < 8; ++j) acc[j] = fmaf((float)v2[j], c2, acc[j]);
#pragma unroll
        for (int j = 0; j < 8; ++j) acc[j] = fmaf((float)v3[j], c3, acc[j]);
        e0 = f0; e1 = f1; e2 = f2; e3 = f3;
    }
    if (g + 4 <= ge) {  // final full quad (entries already in registers)
        h8_t v0 = *(const h8_t*)(hbase + (e0 & 0xFFFFu) * 64);
        h8_t v1 = *(const h8_t*)(hbase + (e1 & 0xFFFFu) * 64);
        h8_t v2 = *(const h8_t*)(hbase + (e2 & 0xFFFFu) * 64);
        h8_t v3 = *(const h8_t*)(hbase + (e3 & 0xFFFFu) * 64);
        float c0 = (float)us_as_h((unsigned short)(e0 >> 16));
        float c1 = (float)us_as_h((unsigned short)(e1 >> 16));
        float c2 = (float)us_as_h((unsigned short)(e2 >> 16));
        float c3 = (float)us_as_h((unsigned short)(e3 >> 16));
#pragma unroll
        for (int j = 0; j < 8; ++j) acc[j] = fmaf((float)v0[j], c0, acc[j]);
#pragma unroll
        for (int j = 0; j < 8; ++j) acc[j] = fmaf((float)v1[j], c1, acc[j]);
#pragma unroll
        for (int j = 0; j < 8; ++j) acc[j] = fmaf((float)v2[j], c2, acc[j]);
#pragma unroll
        for (int j = 0; j < 8; ++j) acc[j] = fmaf((float)v3[j], c3, acc[j]);
        g += 4;
    }
    for (; g < ge; ++g) {
        unsigned e = ep[(size_t)g * 8];
        h8_t v = *(const h8_t*)(hbase + (e & 0xFFFFu) * 64);
        float c = (float)us_as_h((unsigned short)(e >> 16));
#pragma unroll
        for (int j = 0; j < 8; ++j) acc[j] = fmaf((float)v[j], c, acc[j]);
    }
    // reduce edge slots: lanes {c, c+8, ..., c+56} share a batch octet
#pragma unroll
    for (int st = 8; st < 64; st <<= 1) {
#pragma unroll
        for (int j = 0; j < 8; ++j) acc[j] += __shfl_xor(acc[j], st, 64);
    }
    if (lane < 8) {
        float a = alph[k];
        int base = node * 64 + lane * 8;
        float4 h0a = *(const float4*)(h0 + base);
        float4 h0b = *(const float4*)(h0 + base + 4);
        float om = 1.f - a;
        float r0 = fmaf(a, h0a.x, om * acc[0]);
        float r1 = fmaf(a, h0a.y, om * acc[1]);
        float r2 = fmaf(a, h0a.z, om * acc[2]);
        float r3 = fmaf(a, h0a.w, om * acc[3]);
        float r4 = fmaf(a, h0b.x, om * acc[4]);
        float r5 = fmaf(a, h0b.y, om * acc[5]);
        float r6 = fmaf(a, h0b.z, om * acc[6]);
        float r7 = fmaf(a, h0b.w, om * acc[7]);
        if (last) {
            *(float4*)(hF + base)     = make_float4(r0, r1, r2, r3);
            *(float4*)(hF + base + 4) = make_float4(r4, r5, r6, r7);
        } else {
            U4H8 o;
            o.h[0] = (_Float16)r0; o.h[1] = (_Float16)r1;
            o.h[2] = (_Float16)r2; o.h[3] = (_Float16)r3;
            o.h[4] = (_Float16)r4; o.h[5] = (_Float16)r5;
            o.h[6] = (_Float16)r6; o.h[7] = (_Float16)r7;
            *(uint4*)(h_out + base) = o.u;
        }
    }
}

// ---------------- decode (fused LDS transpose of hF [N,64]) ----------------
__global__ __launch_bounds__(256) void decode_kernel(float* __restrict__ y,
                                                     const float* __restrict__ ctl,
                                                     const float* __restrict__ u,
                                                     const float* __restrict__ hF,
                                                     const float* __restrict__ W1,
                                                     const float* __restrict__ b1,
                                                     const float* __restrict__ W2,
                                                     const float* __restrict__ cell_dot) {
    __shared__ float tile[64][65];
    __shared__ float4 pack[HID];
    __shared__ float w2s[HID];
    __shared__ float cds[64];
    if (threadIdx.x < HID) {
        int hh = threadIdx.x;
        pack[hh] = make_float4(W1[0 * HID + hh], W1[1 * HID + hh], W1[2 * HID + hh], b1[hh]);
        w2s[hh] = W2[hh];
        cds[hh] = cell_dot[hh];
    }
    int n0 = blockIdx.x * 64;
    int tx = threadIdx.x & 63, ty = threadIdx.x >> 6;
#pragma unroll
    for (int i = 0; i < 16; ++i) {
        int n = n0 + ty + i * 4;
        tile[ty + i * 4][tx] = (n < N_NODES) ? hF[(size_t)n * 64 + tx] : 0.f;
    }
    __syncthreads();
#pragma unroll
    for (int i = 0; i < 16; ++i) {
        int b = ty + i * 4;
        int n = n0 + tx;
        if (n < N_NODES) {
            size_t idx = (size_t)b * N_NODES + n;
            float xc = ctl[idx], xu = u[idx], xh = tile[tx][b];
            float acc = 0.f;
#pragma unroll 8
            for (int hh = 0; hh < HID; ++hh) {
                float4 p = pack[hh];
                float t = fmaf(xc, p.x, fmaf(xu, p.y, fmaf(xh, p.z, p.w)));
                t = fmaxf(t, 0.f);
                acc = fmaf(t, w2s[hh], acc);
            }
            y[idx] = acc + cds[b];
        }
    }
}

// ---------------- launch ----------------
extern "C" void kernel_launch(void* const* d_in, const int* in_sizes, int n_in,
                              void* d_out, int out_size, void* d_ws, size_t ws_size,
                              hipStream_t stream) {
    const float* ctl          = (const float*)d_in[0];
    const float* u_raw        = (const float*)d_in[1];
    const int*   cell_idx     = (const int*)d_in[2];
    const int*   edge_src     = (const int*)d_in[3];
    const int*   edge_dst     = (const int*)d_in[4];
    const float* edge_val     = (const float*)d_in[5];
    const float* g_logits     = (const float*)d_in[6];
    const float* alpha_logits = (const float*)d_in[7];
    const float* cell_emb     = (const float*)d_in[8];
    const float* W1           = (const float*)d_in[9];
    const float* b1           = (const float*)d_in[10];
    const float* W2           = (const float*)d_in[11];
    const float* b2           = (const float*)d_in[12];
    float* y = (float*)d_out;

    const int TE = in_sizes[3];   // 6 * E
    const int E  = TE / 6;
    const int NB = N_NODES * 64;  // h elements

    char* ws = (char*)d_ws;
    size_t off = 0;
    auto alloc = [&](size_t bytes) -> char* {
        char* p = ws + off;
        off += (bytes + 255) & ~(size_t)255;
        return p;
    };
    int* grp_ptr = (int*)alloc((N_NODES + 1) * sizeof(int));
    int* counts  = (int*)alloc(N_NODES * sizeof(int));
    int* blksum  = (int*)alloc(CBLK * sizeof(int));
    int* blkcnt  = (int*)alloc((size_t)NSLICE * SUBB * SLICE_SZ * sizeof(int));
    int* gcnt    = (int*)alloc((size_t)NB1 * 8 * sizeof(int));
    int* blkoff  = (int*)alloc((size_t)NB1 * 8 * sizeof(int));
    int* bbase   = (int*)alloc(16 * sizeof(int));
    const size_t MAXG = (size_t)TE / 8 + N_NODES + 8;             // padded group bound
    unsigned* eg = (unsigned*)alloc(MAXG * 8 * sizeof(unsigned)); // 32 B/group
    // DISTINCT buffers (no aliasing): ws is 256 MB, total use ~65 MB
    int2* bucket    = (int2*)alloc((size_t)TE * sizeof(int2));
    _Float16* uh    = (_Float16*)alloc((size_t)NB * 2);
    _Float16* hA    = (_Float16*)alloc((size_t)NB * 2);
    _Float16* hB    = (_Float16*)alloc((size_t)NB * 2);
    float* hF       = (float*)alloc((size_t)NB * 4);
    float* u_t      = (float*)alloc((size_t)NB * sizeof(float));
    float* gsign    = (float*)alloc(8 * sizeof(float));
    float* alph     = (float*)alloc(8 * sizeof(float));
    float* cell_dot = (float*)alloc(64 * sizeof(float));

    // 1. CSR build — edges read once, zero global atomics, XCD-local placement
    count8_kernel<<<NB1, 256, 0, stream>>>(edge_dst, gcnt, TE,
                                           (u4_t*)eg, (long long)(MAXG * 2));
    scan8_kernel<<<1, 256, 0, stream>>>(gcnt, blkoff, bbase, g_logits, alpha_logits,
                                        cell_idx, cell_emb, W2, b2,
                                        gsign, alph, cell_dot);
    bucket_kernel<<<NB1, 256, 0, stream>>>(edge_src, edge_dst, edge_val, gsign,
                                           blkoff, bbase, bucket, E, TE);
    hist2db_kernel<<<NBLK, 256, 0, stream>>>(bucket, bbase, blkcnt);
    colscan_kernel<<<CBLK, 256, 0, stream>>>(blkcnt, counts, blksum);
    scan2_kernel<<<CBLK, 256, 0, stream>>>(counts, blksum, grp_ptr, N_NODES);
    // 2. placement + fused u transpose (u_t fp32, uh f16)
    scatter2b_kernel<<<NBLK + TBLK, 256, 0, stream>>>(bucket, bbase, grp_ptr, blkcnt,
                                                      eg, u_raw, u_t, uh);

    // 3. 6 propagation steps: f16 ping-pong, fp32 final into hF
    const _Float16* hin = uh;
    for (int k = 0; k < NSTEPS; ++k) {
        _Float16* hout = (k & 1) ? hB : hA;
        step_kernel<<<(N_NODES + 3) / 4, 256, 0, stream>>>(hin, u_t, hout, hF, grp_ptr,
                                                           eg, alph, k, k == NSTEPS - 1);
        hin = hout;
    }

    // 4. decode (reads hF [N,64] directly via LDS transpose)
    decode_kernel<<<TBLK, 256, 0, stream>>>(y, ctl, u_raw, hF, W1, b1, W2, cell_dot);
}